// Round 4
// baseline (304.500 us; speedup 1.0000x reference)
//
#include <hip/hip_runtime.h>

#define NE 8
#define CAP 1024
#define HD 1024
#define ID 1408
#define TT 2048

typedef __attribute__((ext_vector_type(8))) short bf16x8;
typedef __attribute__((ext_vector_type(4))) float f32x4;
typedef __attribute__((ext_vector_type(4))) unsigned int u32x4;
typedef unsigned short u16;
typedef unsigned int u32;
typedef unsigned long long u64;

__device__ __forceinline__ u16 f2bf(float f) {
  u32 u = __float_as_uint(f);
  u = (u + 0x7fffu + ((u >> 16) & 1u)) >> 16;
  return (u16)u;
}

// HW packed RNE f32->bf16 (gfx950 v_cvt_pk_bf16_f32) — same rounding as f2bf.
__device__ __forceinline__ u32 pk2(float a, float b) {
  u32 r;
  asm("v_cvt_pk_bf16_f32 %0, %1, %2" : "=v"(r) : "v"(a), "v"(b));
  return r;
}
__device__ __forceinline__ u32x4 cvt16(float4 a, float4 b) {
  u32x4 w;
  w.x = pk2(a.x, a.y);
  w.y = pk2(a.z, a.w);
  w.z = pk2(b.x, b.y);
  w.w = pk2(b.z, b.w);
  return w;
}

// ---------------- routing + out-zero (the only remaining "prep") -------------
__global__ __launch_bounds__(256) void route_zero(
    const int* __restrict__ ids, int* __restrict__ rowmap,
    int* __restrict__ counts, float4* __restrict__ out) {
  int b = blockIdx.x;
  int tid = threadIdx.x;
  if (b == 0) {
    __shared__ unsigned char ids_s[TT * 2];
    __shared__ int sc[256][NE + 1];
    for (int i = tid; i < TT * 2; i += 256) ids_s[i] = (unsigned char)ids[i];
    __syncthreads();
    int base = tid * 16;
    u64 own64 = 0;
#pragma unroll
    for (int j = 0; j < 16; ++j) own64 += 1ull << (ids_s[base + j] * 8);
    int own[NE];
#pragma unroll
    for (int e = 0; e < NE; ++e) {
      own[e] = (int)((own64 >> (e * 8)) & 0xff);
      sc[tid][e] = own[e];
    }
    __syncthreads();
    for (int off = 1; off < 256; off <<= 1) {
      int v[NE];
      if (tid >= off) {
#pragma unroll
        for (int e = 0; e < NE; ++e) v[e] = sc[tid - off][e];
      }
      __syncthreads();
      if (tid >= off) {
#pragma unroll
        for (int e = 0; e < NE; ++e) sc[tid][e] += v[e];
      }
      __syncthreads();
    }
    if (tid == 255) {
#pragma unroll
      for (int e = 0; e < NE; ++e) counts[e] = sc[255][e] < CAP ? sc[255][e] : CAP;
    }
    int excl[NE];
#pragma unroll
    for (int e = 0; e < NE; ++e) excl[e] = sc[tid][e] - own[e];
    __syncthreads();
#pragma unroll
    for (int e = 0; e < NE; ++e) sc[tid][e] = excl[e];
#pragma unroll
    for (int j = 0; j < 16; ++j) {
      int f = base + j;
      int e = ids_s[f];
      int p = sc[tid][e]++;
      if (p < CAP) rowmap[e * CAP + p] = f;
    }
    return;
  }
  size_t i = (size_t)(b - 1) * 1024 + tid;  // 512 blocks x 4 float4 = 8.4 MB
  float4 z = {0.f, 0.f, 0.f, 0.f};
  out[i] = z;
  out[i + 256] = z;
  out[i + 512] = z;
  out[i + 768] = z;
}

// ---------------- GEMM1: gathered x(fp32) . w1(fp32)^T, fused cvt + SiLU -----
// 64x128, BK=64, reg-staged double-buffer: global fp32 -> v_cvt_pk_bf16 ->
// ds_write_b128 reproduces the EXACT swizzled LDS image of the old prepped
// path. w1 gate/up interleave is now an inverse index map at pointer setup.
// 48 KB LDS -> 3 blocks/CU keeps the TLP that rounds 0-3 proved essential.
#define G1BUF 24576
__global__ __launch_bounds__(256) void gemm1_kernel(
    const float4* __restrict__ X, const float4* __restrict__ W1, u16* __restrict__ Hb,
    const int* __restrict__ rowmap, const int* __restrict__ counts) {
  int e = blockIdx.x;
  int count = counts[e];
  int m0 = blockIdx.y * 64;
  if (m0 >= count) return;
  int n0 = blockIdx.z * 128;
  int tid = threadIdx.x;
  int lane = tid & 63, wid = tid >> 6;
  int wm = wid >> 1, wn = wid & 1;
  int q = lane >> 4, lm = lane & 15;

  __shared__ __align__(16) char sm[2 * G1BUF];  // per buf: A 8KB @0, B 16KB @8K

  int rloc = tid >> 3;
  int ch = (tid & 7) ^ (rloc & 7);  // pre-swizzled 8-elem chunk index

  const float4* aQ[2];
#pragma unroll
  for (int i = 0; i < 2; ++i) {
    int gr = m0 + rloc + 32 * i;
    int f = (gr < count) ? rowmap[e * CAP + gr] : 0;
    aQ[i] = X + (size_t)(f >> 1) * (HD / 4) + ch * 2;
  }
  const float4* bQ[4];
#pragma unroll
  for (int i = 0; i < 4; ++i) {
    // inverse gate/up interleave: np -> original w1 row n
    int np = n0 + rloc + 32 * i;
    int g = np >> 5, w = np & 31;
    int n = (w < 16) ? (g * 16 + w) : (ID + g * 16 + (w - 16));
    bQ[i] = W1 + ((size_t)e * 2 * ID + n) * (HD / 4) + ch * 2;
  }

  f32x4 zero = {0.f, 0.f, 0.f, 0.f};
  f32x4 acc[2][4];
#pragma unroll
  for (int mi = 0; mi < 2; ++mi)
#pragma unroll
    for (int ni = 0; ni < 4; ++ni) acc[mi][ni] = zero;

  float4 a0, a1, a2, a3, b0, b1, b2, b3, b4, b5, b6, b7;
#define LOAD1(kt)                                                       \
  do {                                                                  \
    int o_ = (kt) * 16;                                                 \
    a0 = aQ[0][o_]; a1 = aQ[0][o_ + 1];                                 \
    a2 = aQ[1][o_]; a3 = aQ[1][o_ + 1];                                 \
    b0 = bQ[0][o_]; b1 = bQ[0][o_ + 1];                                 \
    b2 = bQ[1][o_]; b3 = bQ[1][o_ + 1];                                 \
    b4 = bQ[2][o_]; b5 = bQ[2][o_ + 1];                                 \
    b6 = bQ[3][o_]; b7 = bQ[3][o_ + 1];                                 \
  } while (0)
#define CVTW1(base)                                                     \
  do {                                                                  \
    char* sb_ = (base);                                                 \
    *(u32x4*)(sb_ + tid * 16) = cvt16(a0, a1);                          \
    *(u32x4*)(sb_ + 4096 + tid * 16) = cvt16(a2, a3);                   \
    *(u32x4*)(sb_ + 8192 + tid * 16) = cvt16(b0, b1);                   \
    *(u32x4*)(sb_ + 12288 + tid * 16) = cvt16(b2, b3);                  \
    *(u32x4*)(sb_ + 16384 + tid * 16) = cvt16(b4, b5);                  \
    *(u32x4*)(sb_ + 20480 + tid * 16) = cvt16(b6, b7);                  \
  } while (0)

  LOAD1(0);
  CVTW1(sm);
  __syncthreads();
  for (int kt = 0; kt < HD / 64; ++kt) {
    char* cb = sm + (kt & 1) * G1BUF;
    char* nb = sm + ((kt & 1) ^ 1) * G1BUF;
    if (kt < HD / 64 - 1) LOAD1(kt + 1);  // issue next-step loads early
#pragma unroll
    for (int s = 0; s < 2; ++s) {
      int cs = ((s * 4 + q) ^ (lm & 7)) * 16;
      bf16x8 af[2], bfr[4];
#pragma unroll
      for (int mi = 0; mi < 2; ++mi)
        af[mi] = *(const bf16x8*)(cb + (wm * 32 + mi * 16 + lm) * 128 + cs);
#pragma unroll
      for (int ni = 0; ni < 4; ++ni)
        bfr[ni] = *(const bf16x8*)(cb + 8192 + (wn * 64 + ni * 16 + lm) * 128 + cs);
      __builtin_amdgcn_s_setprio(1);
#pragma unroll
      for (int mi = 0; mi < 2; ++mi)
#pragma unroll
        for (int ni = 0; ni < 4; ++ni)
          acc[mi][ni] = __builtin_amdgcn_mfma_f32_16x16x32_bf16(af[mi], bfr[ni], acc[mi][ni], 0, 0, 0);
      __builtin_amdgcn_s_setprio(0);
    }
    if (kt < HD / 64 - 1) CVTW1(nb);  // cvt+write after MFMA (loads landed)
    __syncthreads();
  }

  // ---- fused SiLU epilogue (unchanged): merged 64x64 u16 tile ----
  u16* smOut = (u16*)sm;  // [64][72] u16
#pragma unroll
  for (int mi = 0; mi < 2; ++mi) {
#pragma unroll
    for (int k = 0; k < 2; ++k) {
      int colL = wn * 32 + k * 16 + lm;
#pragma unroll
      for (int r = 0; r < 4; ++r) {
        float g = acc[mi][2 * k][r];
        float u = acc[mi][2 * k + 1][r];
        float a = g / (1.f + __expf(-g)) * u;
        int row = wm * 32 + mi * 16 + q * 4 + r;
        smOut[row * 72 + colL] = f2bf(a);
      }
    }
  }
  __syncthreads();
  {
    int row = tid >> 2, seg = tid & 3;
    const u16* sp = smOut + row * 72 + seg * 16;
    bf16x8 v0 = *(const bf16x8*)sp;
    bf16x8 v1 = *(const bf16x8*)(sp + 8);
    u16* dp = Hb + ((size_t)e * CAP + m0 + row) * ID + (n0 >> 1) + seg * 16;
    *(bf16x8*)dp = v0;
    *(bf16x8*)(dp + 8) = v1;
  }
}

// ---------------- GEMM2: act(bf16) . w2(fp32)^T, fused cvt + combine ---------
// 64x64, BK=64, reg-staged double-buffer; A from hbuf (bf16, no cvt),
// B from w2 fp32 via cvt_pk. 32 KB LDS -> 5 blocks/CU.
#define G2BUF 16384
__global__ __launch_bounds__(256) void gemm2_kernel(
    const u16* __restrict__ A, const float4* __restrict__ W2, float* __restrict__ out,
    const int* __restrict__ rowmap, const int* __restrict__ counts,
    const float* __restrict__ tw) {
  int e = blockIdx.x;
  int count = counts[e];
  int m0 = blockIdx.y * 64;
  if (m0 >= count) return;
  int n0 = blockIdx.z * 64;
  int tid = threadIdx.x;
  int lane = tid & 63, wid = tid >> 6;
  int wm = wid >> 1, wn = wid & 1;
  int q = lane >> 4, lm = lane & 15;

  __shared__ __align__(16) char sm[2 * G2BUF];  // per buf: A 8KB @0, B 8KB @8K

  int rloc = tid >> 3;
  int ch = (tid & 7) ^ (rloc & 7);

  const u32x4* aU[2];
#pragma unroll
  for (int i = 0; i < 2; ++i)
    aU[i] = (const u32x4*)A + (size_t)(e * CAP + m0 + rloc + 32 * i) * (ID / 8) + ch;
  const float4* bQ[2];
#pragma unroll
  for (int i = 0; i < 2; ++i)
    bQ[i] = W2 + ((size_t)e * HD + n0 + rloc + 32 * i) * (ID / 4) + ch * 2;

  f32x4 zero = {0.f, 0.f, 0.f, 0.f};
  f32x4 acc[2][2];
#pragma unroll
  for (int mi = 0; mi < 2; ++mi)
#pragma unroll
    for (int ni = 0; ni < 2; ++ni) acc[mi][ni] = zero;

  u32x4 A0, A1;
  float4 c0, c1, c2, c3;
#define LOAD2(kt)                                                       \
  do {                                                                  \
    A0 = aU[0][(kt) * 8]; A1 = aU[1][(kt) * 8];                         \
    c0 = bQ[0][(kt) * 16]; c1 = bQ[0][(kt) * 16 + 1];                   \
    c2 = bQ[1][(kt) * 16]; c3 = bQ[1][(kt) * 16 + 1];                   \
  } while (0)
#define CVTW2(base)                                                     \
  do {                                                                  \
    char* sb_ = (base);                                                 \
    *(u32x4*)(sb_ + tid * 16) = A0;                                     \
    *(u32x4*)(sb_ + 4096 + tid * 16) = A1;                              \
    *(u32x4*)(sb_ + 8192 + tid * 16) = cvt16(c0, c1);                   \
    *(u32x4*)(sb_ + 12288 + tid * 16) = cvt16(c2, c3);                  \
  } while (0)

  LOAD2(0);
  CVTW2(sm);
  __syncthreads();
  for (int kt = 0; kt < ID / 64; ++kt) {
    char* cb = sm + (kt & 1) * G2BUF;
    char* nb = sm + ((kt & 1) ^ 1) * G2BUF;
    if (kt < ID / 64 - 1) LOAD2(kt + 1);
#pragma unroll
    for (int s = 0; s < 2; ++s) {
      int cs = ((s * 4 + q) ^ (lm & 7)) * 16;
      bf16x8 af[2], bfr[2];
#pragma unroll
      for (int mi = 0; mi < 2; ++mi)
        af[mi] = *(const bf16x8*)(cb + (wm * 32 + mi * 16 + lm) * 128 + cs);
#pragma unroll
      for (int ni = 0; ni < 2; ++ni)
        bfr[ni] = *(const bf16x8*)(cb + 8192 + (wn * 32 + ni * 16 + lm) * 128 + cs);
      __builtin_amdgcn_s_setprio(1);
#pragma unroll
      for (int mi = 0; mi < 2; ++mi)
#pragma unroll
        for (int ni = 0; ni < 2; ++ni)
          acc[mi][ni] = __builtin_amdgcn_mfma_f32_16x16x32_bf16(af[mi], bfr[ni], acc[mi][ni], 0, 0, 0);
      __builtin_amdgcn_s_setprio(0);
    }
    if (kt < ID / 64 - 1) CVTW2(nb);
    __syncthreads();
  }

  // fused combine epilogue: out[token, col] += w * y
#pragma unroll
  for (int mi = 0; mi < 2; ++mi) {
#pragma unroll
    for (int r = 0; r < 4; ++r) {
      int grow = m0 + wm * 32 + mi * 16 + q * 4 + r;
      if (grow < count) {
        int f = rowmap[e * CAP + grow];
        float w = tw[f];
        int t = f >> 1;
#pragma unroll
        for (int ni = 0; ni < 2; ++ni) {
          int col = n0 + wn * 32 + ni * 16 + lm;
          atomicAdd(&out[(size_t)t * HD + col], w * acc[mi][ni][r]);
        }
      }
    }
  }
}

extern "C" void kernel_launch(void* const* d_in, const int* in_sizes, int n_in,
                              void* d_out, int out_size, void* d_ws, size_t ws_size,
                              hipStream_t stream) {
  const float* hidden = (const float*)d_in[0];
  const float* w1 = (const float*)d_in[1];
  const float* w2 = (const float*)d_in[2];
  const float* tw = (const float*)d_in[3];
  const int* ids = (const int*)d_in[4];
  float* out = (float*)d_out;

  char* p = (char*)d_ws;
  auto alloc = [&](size_t b) { char* r = p; p += (b + 255) & ~(size_t)255; return r; };
  u16* hbuf = (u16*)alloc((size_t)NE * CAP * ID * 2);  // 23.1 MB
  int* rowmap = (int*)alloc((size_t)NE * CAP * 4);
  int* counts = (int*)alloc((size_t)NE * 4);

  // routing (block 0) + out zeroing — the conversion pass is GONE
  route_zero<<<513, 256, 0, stream>>>(ids, rowmap, counts, (float4*)out);

  // GEMM1 + fused fp32->bf16 + SiLU: hbuf = silu(x.w1g^T) * (x.w1u^T)
  gemm1_kernel<<<dim3(NE, CAP / 64, 2 * ID / 128), 256, 0, stream>>>(
      (const float4*)hidden, (const float4*)w1, hbuf, rowmap, counts);

  // GEMM2 + fused fp32->bf16 + combine: out[t,:] += w * (act . w2^T)
  gemm2_kernel<<<dim3(NE, CAP / 64, HD / 64), 256, 0, stream>>>(
      hbuf, (const float4*)w2, out, rowmap, counts, tw);
}

// Round 5
// 256.689 us; speedup vs baseline: 1.1863x; 1.1863x over previous
//
#include <hip/hip_runtime.h>

#define NE 8
#define CAP 1024
#define HD 1024
#define ID 1408
#define TT 2048

typedef __attribute__((ext_vector_type(8))) short bf16x8;
typedef __attribute__((ext_vector_type(4))) float f32x4;
typedef unsigned short u16;
typedef unsigned int u32;
typedef unsigned long long u64;

__device__ __forceinline__ u16 f2bf(float f) {
  u32 u = __float_as_uint(f);
  u = (u + 0x7fffu + ((u >> 16) & 1u)) >> 16;
  return (u16)u;
}

__device__ __forceinline__ bf16x8 pack8(float4 a, float4 b) {
  bf16x8 r;
  r[0] = (short)f2bf(a.x); r[1] = (short)f2bf(a.y);
  r[2] = (short)f2bf(a.z); r[3] = (short)f2bf(a.w);
  r[4] = (short)f2bf(b.x); r[5] = (short)f2bf(b.y);
  r[6] = (short)f2bf(b.z); r[7] = (short)f2bf(b.w);
  return r;
}

__device__ __forceinline__ void async_cp16(const void* g, void* l) {
  __builtin_amdgcn_global_load_lds(
      (const __attribute__((address_space(1))) u32*)g,
      (__attribute__((address_space(3))) u32*)l, 16, 0, 0);
}

// ---------------- prep: route (block 0) + w1 il-cvt + x cvt ------------------
// r0-proven small-block streaming form (1 float4/thread). w2 cvt and out-zero
// moved OUT of here: they ride inside the gemm1 launch (only needed by gemm2).
#define W1ROWS (NE * 2 * ID)       // 22528 blocks, one per (row,expert)
#define XBLK (TT * HD / 4 / 256)   // 2048 blocks
__global__ __launch_bounds__(256) void prep_kernel(
    const float4* __restrict__ w1, ushort4* __restrict__ bw1,
    const float4* __restrict__ x, ushort4* __restrict__ bx,
    const int* __restrict__ ids, int* __restrict__ rowmap,
    int* __restrict__ counts) {
  int b = blockIdx.x;
  int tid = threadIdx.x;
  if (b == 0) {
    // ---- routing: exact flat-order cumsum positions ----
    __shared__ unsigned char ids_s[TT * 2];
    __shared__ int sc[256][NE + 1];
    for (int i = tid; i < TT * 2; i += 256) ids_s[i] = (unsigned char)ids[i];
    __syncthreads();
    int base = tid * 16;
    u64 own64 = 0;
#pragma unroll
    for (int j = 0; j < 16; ++j) own64 += 1ull << (ids_s[base + j] * 8);
    int own[NE];
#pragma unroll
    for (int e = 0; e < NE; ++e) {
      own[e] = (int)((own64 >> (e * 8)) & 0xff);
      sc[tid][e] = own[e];
    }
    __syncthreads();
    for (int off = 1; off < 256; off <<= 1) {
      int v[NE];
      if (tid >= off) {
#pragma unroll
        for (int e = 0; e < NE; ++e) v[e] = sc[tid - off][e];
      }
      __syncthreads();
      if (tid >= off) {
#pragma unroll
        for (int e = 0; e < NE; ++e) sc[tid][e] += v[e];
      }
      __syncthreads();
    }
    if (tid == 255) {
#pragma unroll
      for (int e = 0; e < NE; ++e) counts[e] = sc[255][e] < CAP ? sc[255][e] : CAP;
    }
    int excl[NE];
#pragma unroll
    for (int e = 0; e < NE; ++e) excl[e] = sc[tid][e] - own[e];
    __syncthreads();
#pragma unroll
    for (int e = 0; e < NE; ++e) sc[tid][e] = excl[e];
#pragma unroll
    for (int j = 0; j < 16; ++j) {
      int f = base + j;
      int e = ids_s[f];
      int p = sc[tid][e]++;
      if (p < CAP) rowmap[e * CAP + p] = f;
    }
    return;
  }
  int bb = b - 1;
  if (bb < W1ROWS) {
    // w1 interleave-cvt: gate j -> (j>>4)*32+(j&15), up -> +16
    int n = bb % (2 * ID);
    int e = bb / (2 * ID);
    int j = (n < ID) ? n : (n - ID);
    int np = (j >> 4) * 32 + (j & 15) + ((n < ID) ? 0 : 16);
    float4 v = w1[((size_t)e * 2 * ID + n) * (HD / 4) + tid];
    ushort4 o;
    o.x = f2bf(v.x); o.y = f2bf(v.y); o.z = f2bf(v.z); o.w = f2bf(v.w);
    bw1[((size_t)e * 2 * ID + np) * (HD / 4) + tid] = o;
  } else {
    size_t i = (size_t)(bb - W1ROWS) * 256 + tid;
    float4 v = x[i];
    ushort4 o;
    o.x = f2bf(v.x); o.y = f2bf(v.y); o.z = f2bf(v.z); o.w = f2bf(v.w);
    bx[i] = o;
  }
}

// ---------------- GEMM1 (+ riders): 64x128, depth-2 counted-vmcnt pipeline ----
// bid<704: w2 fp32->bf16 cvt riders (4x16KB units each). bid in [704,768):
// out-zero riders. bid>=768: gemm1 tiles (r3-verbatim pipeline: 3x24KB LDS
// rotation, stage(t+2) in step t, s_waitcnt vmcnt(6)+s_barrier fused, never
// drained to 0 in the main loop). Riders run during gemm1's BW/occupancy
// slack; kernel boundary orders them before gemm2.
#define G1BUF 24576
__global__ __launch_bounds__(256) void gemm1_kernel(
    const u16* __restrict__ A, const u16* __restrict__ B, u16* __restrict__ Hb,
    const int* __restrict__ rowmap, const int* __restrict__ counts,
    const float4* __restrict__ W2, bf16x8* __restrict__ bw2,
    float4* __restrict__ outz) {
  int bid = blockIdx.x;
  int tid = threadIdx.x;
  if (bid < 704) {  // ---- w2 cvt riders: 704 x 4 units = 2816 x 16KB ----
#pragma unroll
    for (int k2 = 0; k2 < 4; ++k2) {
      size_t base4 = ((size_t)bid * 4 + k2) * 1024;
      float4 v0 = W2[base4 + tid * 2];
      float4 v1 = W2[base4 + tid * 2 + 1];
      float4 v2 = W2[base4 + 512 + tid * 2];
      float4 v3 = W2[base4 + 512 + tid * 2 + 1];
      bf16x8* dst = bw2 + base4 / 2;
      dst[tid] = pack8(v0, v1);
      dst[256 + tid] = pack8(v2, v3);
    }
    return;
  }
  if (bid < 768) {  // ---- out-zero riders: 64 blocks x 8192 float4 ----
    size_t base = (size_t)(bid - 704) * 8192;
    float4 z = {0.f, 0.f, 0.f, 0.f};
#pragma unroll
    for (int i2 = 0; i2 < 32; ++i2) outz[base + i2 * 256 + tid] = z;
    return;
  }
  int g = bid - 768;
  int e = g & 7;
  int m0 = ((g >> 3) & 15) * 64;
  int n0 = (g >> 7) * 128;
  int count = counts[e];
  if (m0 >= count) return;
  int lane = tid & 63, wid = tid >> 6;
  int wm = wid >> 1, wn = wid & 1;
  int q = lane >> 4, lm = lane & 15;

  __shared__ __align__(16) char sm[3 * G1BUF];  // per buf: A 8KB @0, B 16KB @8K

  int rloc = tid >> 3;
  int chs = ((tid & 7) ^ (rloc & 7)) * 8;
  const u16* aP[2];
  const u16* bP[4];
#pragma unroll
  for (int i = 0; i < 2; ++i) {
    int gr = m0 + rloc + 32 * i;
    int f = (gr < count) ? rowmap[e * CAP + gr] : 0;
    aP[i] = A + (size_t)(f >> 1) * HD + chs;
  }
#pragma unroll
  for (int i = 0; i < 4; ++i)
    bP[i] = B + ((size_t)e * 2 * ID + n0 + rloc + 32 * i) * HD + chs;

  f32x4 zero = {0.f, 0.f, 0.f, 0.f};
  f32x4 acc[2][4];
#pragma unroll
  for (int mi = 0; mi < 2; ++mi)
#pragma unroll
    for (int ni = 0; ni < 4; ++ni) acc[mi][ni] = zero;

#define STAGE1(base, kt)                                             \
  do {                                                               \
    int ko_ = (kt) * 64;                                             \
    char* sb_ = (base);                                              \
    async_cp16(aP[0] + ko_, sb_ + (0 * 256 + tid) * 16);             \
    async_cp16(aP[1] + ko_, sb_ + (1 * 256 + tid) * 16);             \
    async_cp16(bP[0] + ko_, sb_ + 8192 + (0 * 256 + tid) * 16);      \
    async_cp16(bP[1] + ko_, sb_ + 8192 + (1 * 256 + tid) * 16);      \
    async_cp16(bP[2] + ko_, sb_ + 8192 + (2 * 256 + tid) * 16);      \
    async_cp16(bP[3] + ko_, sb_ + 8192 + (3 * 256 + tid) * 16);      \
  } while (0)

  STAGE1(sm, 0);
  STAGE1(sm + G1BUF, 1);
  int p = 0, pn2 = 2;
  for (int kt = 0; kt < HD / 64; ++kt) {
    if (kt == HD / 64 - 1)
      asm volatile("s_waitcnt vmcnt(0)\ns_barrier" ::: "memory");
    else
      asm volatile("s_waitcnt vmcnt(6)\ns_barrier" ::: "memory");
    const char* sb = sm + p * G1BUF;
    if (kt + 2 < HD / 64) STAGE1(sm + pn2 * G1BUF, kt + 2);
#pragma unroll
    for (int s = 0; s < 2; ++s) {
      int cs = ((s * 4 + q) ^ (lm & 7)) * 16;
      bf16x8 af[2], bfr[4];
#pragma unroll
      for (int mi = 0; mi < 2; ++mi)
        af[mi] = *(const bf16x8*)(sb + (wm * 32 + mi * 16 + lm) * 128 + cs);
#pragma unroll
      for (int ni = 0; ni < 4; ++ni)
        bfr[ni] = *(const bf16x8*)(sb + 8192 + (wn * 64 + ni * 16 + lm) * 128 + cs);
      __builtin_amdgcn_s_setprio(1);
#pragma unroll
      for (int mi = 0; mi < 2; ++mi)
#pragma unroll
        for (int ni = 0; ni < 4; ++ni)
          acc[mi][ni] = __builtin_amdgcn_mfma_f32_16x16x32_bf16(af[mi], bfr[ni], acc[mi][ni], 0, 0, 0);
      __builtin_amdgcn_s_setprio(0);
    }
    p = (p == 2) ? 0 : p + 1;
    pn2 = (pn2 == 2) ? 0 : pn2 + 1;
  }
  __syncthreads();  // full drain before LDS reuse by epilogue

  // ---- fused SiLU epilogue: merged 64x64 u16 tile ----
  u16* smOut = (u16*)sm;  // [64][72] u16
#pragma unroll
  for (int mi = 0; mi < 2; ++mi) {
#pragma unroll
    for (int k = 0; k < 2; ++k) {
      int colL = wn * 32 + k * 16 + lm;
#pragma unroll
      for (int r = 0; r < 4; ++r) {
        float g2 = acc[mi][2 * k][r];
        float u = acc[mi][2 * k + 1][r];
        float a = g2 / (1.f + __expf(-g2)) * u;
        int row = wm * 32 + mi * 16 + q * 4 + r;
        smOut[row * 72 + colL] = f2bf(a);
      }
    }
  }
  __syncthreads();
  {
    int row = tid >> 2, seg = tid & 3;
    const u16* sp = smOut + row * 72 + seg * 16;
    bf16x8 v0 = *(const bf16x8*)sp;
    bf16x8 v1 = *(const bf16x8*)(sp + 8);
    u16* dp = Hb + ((size_t)e * CAP + m0 + row) * ID + (n0 >> 1) + seg * 16;
    *(bf16x8*)dp = v0;
    *(bf16x8*)(dp + 8) = v1;
  }
}

// ---------------- GEMM2: 64x64, depth-2 counted-vmcnt pipeline (r3-verbatim) --
#define G2BUF 16384
__global__ __launch_bounds__(256) void gemm2_kernel(
    const u16* __restrict__ A, const u16* __restrict__ B, float* __restrict__ out,
    const int* __restrict__ rowmap, const int* __restrict__ counts,
    const float* __restrict__ tw) {
  int e = blockIdx.x;
  int count = counts[e];
  int m0 = blockIdx.y * 64;
  if (m0 >= count) return;
  int n0 = blockIdx.z * 64;
  int tid = threadIdx.x;
  int lane = tid & 63, wid = tid >> 6;
  int wm = wid >> 1, wn = wid & 1;
  int q = lane >> 4, lm = lane & 15;

  __shared__ __align__(16) char sm[3 * G2BUF];  // per buf: A 8KB @0, B 8KB @8K

  int rloc = tid >> 3;
  int chs = ((tid & 7) ^ (rloc & 7)) * 8;
  const u16* aP[2];
  const u16* bP[2];
#pragma unroll
  for (int i = 0; i < 2; ++i) {
    aP[i] = A + ((size_t)e * CAP + m0 + rloc + 32 * i) * ID + chs;
    bP[i] = B + ((size_t)e * HD + n0 + rloc + 32 * i) * ID + chs;
  }

  f32x4 zero = {0.f, 0.f, 0.f, 0.f};
  f32x4 acc[2][2];
#pragma unroll
  for (int mi = 0; mi < 2; ++mi)
#pragma unroll
    for (int ni = 0; ni < 2; ++ni) acc[mi][ni] = zero;

#define STAGE2(base, kt)                                             \
  do {                                                               \
    int ko_ = (kt) * 64;                                             \
    char* sb_ = (base);                                              \
    async_cp16(aP[0] + ko_, sb_ + (0 * 256 + tid) * 16);             \
    async_cp16(aP[1] + ko_, sb_ + (1 * 256 + tid) * 16);             \
    async_cp16(bP[0] + ko_, sb_ + 8192 + (0 * 256 + tid) * 16);      \
    async_cp16(bP[1] + ko_, sb_ + 8192 + (1 * 256 + tid) * 16);      \
  } while (0)

  STAGE2(sm, 0);
  STAGE2(sm + G2BUF, 1);
  int p = 0, pn2 = 2;
  for (int kt = 0; kt < ID / 64; ++kt) {
    if (kt == ID / 64 - 1)
      asm volatile("s_waitcnt vmcnt(0)\ns_barrier" ::: "memory");
    else
      asm volatile("s_waitcnt vmcnt(4)\ns_barrier" ::: "memory");
    const char* sb = sm + p * G2BUF;
    if (kt + 2 < ID / 64) STAGE2(sm + pn2 * G2BUF, kt + 2);
#pragma unroll
    for (int s = 0; s < 2; ++s) {
      int cs = ((s * 4 + q) ^ (lm & 7)) * 16;
      bf16x8 af[2], bfr[2];
#pragma unroll
      for (int mi = 0; mi < 2; ++mi)
        af[mi] = *(const bf16x8*)(sb + (wm * 32 + mi * 16 + lm) * 128 + cs);
#pragma unroll
      for (int ni = 0; ni < 2; ++ni)
        bfr[ni] = *(const bf16x8*)(sb + 8192 + (wn * 32 + ni * 16 + lm) * 128 + cs);
      __builtin_amdgcn_s_setprio(1);
#pragma unroll
      for (int mi = 0; mi < 2; ++mi)
#pragma unroll
        for (int ni = 0; ni < 2; ++ni)
          acc[mi][ni] = __builtin_amdgcn_mfma_f32_16x16x32_bf16(af[mi], bfr[ni], acc[mi][ni], 0, 0, 0);
      __builtin_amdgcn_s_setprio(0);
    }
    p = (p == 2) ? 0 : p + 1;
    pn2 = (pn2 == 2) ? 0 : pn2 + 1;
  }

  // fused combine epilogue: out[token, col] += w * y
#pragma unroll
  for (int mi = 0; mi < 2; ++mi) {
#pragma unroll
    for (int r = 0; r < 4; ++r) {
      int grow = m0 + wm * 32 + mi * 16 + q * 4 + r;
      if (grow < count) {
        int f = rowmap[e * CAP + grow];
        float w = tw[f];
        int t = f >> 1;
#pragma unroll
        for (int ni = 0; ni < 2; ++ni) {
          int col = n0 + wn * 32 + ni * 16 + lm;
          atomicAdd(&out[(size_t)t * HD + col], w * acc[mi][ni][r]);
        }
      }
    }
  }
}

extern "C" void kernel_launch(void* const* d_in, const int* in_sizes, int n_in,
                              void* d_out, int out_size, void* d_ws, size_t ws_size,
                              hipStream_t stream) {
  const float* hidden = (const float*)d_in[0];
  const float* w1 = (const float*)d_in[1];
  const float* w2 = (const float*)d_in[2];
  const float* tw = (const float*)d_in[3];
  const int* ids = (const int*)d_in[4];
  float* out = (float*)d_out;

  char* p = (char*)d_ws;
  auto alloc = [&](size_t b) { char* r = p; p += (b + 255) & ~(size_t)255; return r; };
  u16* bw1 = (u16*)alloc((size_t)NE * 2 * ID * HD * 2);   // 46.1 MB (interleaved)
  u16* bw2 = (u16*)alloc((size_t)NE * HD * ID * 2);        // 23.1 MB
  u16* bx = (u16*)alloc((size_t)TT * HD * 2);              // 4.2 MB
  u16* hbuf = (u16*)alloc((size_t)NE * CAP * ID * 2);      // 23.1 MB
  int* rowmap = (int*)alloc((size_t)NE * CAP * 4);
  int* counts = (int*)alloc((size_t)NE * 4);

  // prep: route (block 0) + w1 il-cvt + x cvt  (w2/out-zero moved to riders)
  prep_kernel<<<1 + W1ROWS + XBLK, 256, 0, stream>>>(
      (const float4*)w1, (ushort4*)bw1, (const float4*)hidden, (ushort4*)bx,
      ids, rowmap, counts);

  // GEMM1 + SiLU, with w2-cvt and out-zero riding as the first 768 blocks
  gemm1_kernel<<<768 + NE * (CAP / 64) * (2 * ID / 128), 256, 0, stream>>>(
      bx, bw1, hbuf, rowmap, counts, (const float4*)w2, (bf16x8*)bw2,
      (float4*)out);

  // GEMM2 + combine: out[t,:] += w * (act . w2^T)
  gemm2_kernel<<<dim3(NE, CAP / 64, HD / 64), 256, 0, stream>>>(
      hbuf, bw2, out, rowmap, counts, tw);
}